// Round 5
// baseline (388.500 us; speedup 1.0000x reference)
//
#include <hip/hip_runtime.h>
#include <math.h>

// LinearAttention B=16 L=8192 D=256 H=4 dh=32 — fused-dataflow version
//   prep:    W_qkv cols 128..383 -> WT hi/lo bf16 [256 col][256 k]
//   gemm_kv: per 64-row block: [64x256]@[256x256] (split-bf16 MFMA) -> k,v in acc
//            -> exp(k)|v fp32 tile in LDS (two 32-row half-passes, 33 KB) ->
//            VALU outer-product -> S_part, Z_part (no atomics)
//   reduce:  S = sum_j S_part[j], Z = sum_j Z_part[j]  (coalesced, 256 blocks)
//   combine: ctx = S/Z; M2 = scale*ctx@W_out (fp32)
//   w2eff:   W2[b] = Wq @ M2[b]  ->  hi/lo bf16 [b][n][k]  (q folded:
//            out = (x@Wq)@M2 = x@(Wq@M2))
//   gemm2:   out[b] = x[b] @ W2[b] + b_out   (A = x fp32 split in-kernel, K=256)
// Split precision: a=hi+lo; keep Ah*Bh+Ah*Bl+Al*Bh (drop ~2^-18 Al*Bl term).
// gemm_kv LDS = 40960 B (staging union epilogue tile) -> 4 blocks/CU.

typedef __attribute__((ext_vector_type(8))) short bf16x8;
typedef __attribute__((ext_vector_type(4))) float f32x4;
typedef __attribute__((ext_vector_type(4))) unsigned u32x4;

__device__ __forceinline__ unsigned cvt_pk2(float a, float b) {
    unsigned r;
    asm("v_cvt_pk_bf16_f32 %0, %1, %2" : "=v"(r) : "v"(a), "v"(b));
    return r;
}
__device__ __forceinline__ ushort bf16_rn(float f) {
    return (ushort)cvt_pk2(f, f);
}
__device__ __forceinline__ float bf16f(ushort h) { return __uint_as_float(((unsigned)h) << 16); }

__device__ __forceinline__ void glds16(const void* g, void* l) {
    __builtin_amdgcn_global_load_lds((const __attribute__((address_space(1))) unsigned int*)g,
                                     (__attribute__((address_space(3))) unsigned int*)l,
                                     16, 0, 0);
}

// W_qkv [256,384] cols 128..383 -> WT hi/lo bf16 [256 col][256 k]
__global__ __launch_bounds__(256) void prep_kernel(const float* __restrict__ W,
                                                   ushort* __restrict__ wh,
                                                   ushort* __restrict__ wl) {
    int n = blockIdx.x, k = threadIdx.x;          // n: local col (qkv col 128+n)
    float f = W[k * 384 + 128 + n];
    ushort h = bf16_rn(f);
    wh[n * 256 + k] = h;
    wl[n * 256 + k] = bf16_rn(f - bf16f(h));
}

// gemm_kv: grid 2048 (64-row tiles), 256 thr = 4 waves; wave w owns cols w*64..+63.
__global__ __launch_bounds__(256) void gemm_kv(
    const float* __restrict__ X,
    const ushort* __restrict__ Wh, const ushort* __restrict__ Wl,
    float* __restrict__ S_part, float* __restrict__ Z_part) {
    __shared__ __align__(16) char smem[40960];
    float*  As  = (float*)smem;                 // [8 seg][256 f] = 8 KB, chunk p = q^(r&7)
    ushort* Bsh = (ushort*)(smem + 8192);       // [16 seg][512] = 16 KB, p = q^((r>>1)&3)
    ushort* Bsl = (ushort*)(smem + 8192 + 16384);
    float*  tile = (float*)smem;                // epilogue: [32][260] fp32 ek|v = 33 KB

    const int tid = threadIdx.x;
    const int blk = blockIdx.x;
    const long row0 = (long)blk * 64;
    const int lane = tid & 63, wave = tid >> 6;
    const int wc = wave * 64;
    const int m = lane & 15, quad = lane >> 4;
    const int ra = lane >> 3, pa = lane & 7;
    const int rb = lane >> 2, pb = lane & 3;

    f32x4 acc[4][4] = {};

    for (int k0 = 0; k0 < 256; k0 += 32) {
#pragma unroll
        for (int s = 0; s < 2; ++s) {          // A: 8 segs of 1KB
            int seg = s * 4 + wave;
            int r = seg * 8 + ra;
            int q = pa ^ (r & 7);
            glds16(&X[(row0 + r) * 256 + k0 + q * 4], &As[seg * 256]);
        }
#pragma unroll
        for (int s = 0; s < 4; ++s) {          // Bh/Bl: 16 segs each
            int seg = s * 4 + wave;
            int r = seg * 16 + rb;
            int q = pb ^ ((r >> 1) & 3);
            glds16(&Wh[r * 256 + k0 + q * 8], &Bsh[seg * 512]);
            glds16(&Wl[r * 256 + k0 + q * 8], &Bsl[seg * 512]);
        }
        __syncthreads();

        bf16x8 bh[4], bl[4];
#pragma unroll
        for (int j = 0; j < 4; ++j) {
            int r = wc + j * 16 + m;
            int p = quad ^ ((r >> 1) & 3);
            bh[j] = *(const bf16x8*)&Bsh[r * 32 + p * 8];
            bl[j] = *(const bf16x8*)&Bsl[r * 32 + p * 8];
        }
#pragma unroll
        for (int i = 0; i < 4; ++i) {
            int r = i * 16 + m;
            int p0 = (quad * 2) ^ (r & 7);
            int p1 = (quad * 2 + 1) ^ (r & 7);
            f32x4 a0 = *(const f32x4*)&As[r * 32 + p0 * 4];
            f32x4 a1 = *(const f32x4*)&As[r * 32 + p1 * 4];
            u32x4 ahw, alw;
#pragma unroll
            for (int e = 0; e < 2; ++e) {
                float f0 = a0[2 * e], f1 = a0[2 * e + 1];
                unsigned h = cvt_pk2(f0, f1);
                ahw[e] = h;
                alw[e] = cvt_pk2(f0 - __uint_as_float(h << 16),
                                 f1 - __uint_as_float(h & 0xFFFF0000u));
            }
#pragma unroll
            for (int e = 0; e < 2; ++e) {
                float f0 = a1[2 * e], f1 = a1[2 * e + 1];
                unsigned h = cvt_pk2(f0, f1);
                ahw[2 + e] = h;
                alw[2 + e] = cvt_pk2(f0 - __uint_as_float(h << 16),
                                     f1 - __uint_as_float(h & 0xFFFF0000u));
            }
            bf16x8 ah = __builtin_bit_cast(bf16x8, ahw);
            bf16x8 al = __builtin_bit_cast(bf16x8, alw);
#pragma unroll
            for (int j = 0; j < 4; ++j) {
                acc[i][j] = __builtin_amdgcn_mfma_f32_16x16x32_bf16(ah, bh[j], acc[i][j], 0, 0, 0);
                acc[i][j] = __builtin_amdgcn_mfma_f32_16x16x32_bf16(ah, bl[j], acc[i][j], 0, 0, 0);
                acc[i][j] = __builtin_amdgcn_mfma_f32_16x16x32_bf16(al, bh[j], acc[i][j], 0, 0, 0);
            }
        }
        __syncthreads();
    }

    // epilogue: two 32-row half-passes; tile[32][260] cols 0..127 = e^k, 128..255 = v
    const int h = wave, d = lane >> 1, eg = lane & 1, e0 = eg * 16;
    float sacc[16] = {};
    float z = 0.f;
    for (int half = 0; half < 2; ++half) {
        if (half) __syncthreads();             // all waves done reading pass-0 tile
#pragma unroll
        for (int ii = 0; ii < 2; ++ii) {
            int i = half * 2 + ii;
#pragma unroll
            for (int r4 = 0; r4 < 4; ++r4) {
                int rl = ii * 16 + quad * 4 + r4;     // 0..31
#pragma unroll
                for (int j = 0; j < 4; ++j) {
                    int c = wc + j * 16 + m;
                    float v = acc[i][j][r4];
                    tile[rl * 260 + c] = (c < 128) ? __expf(v) : v;
                }
            }
        }
        __syncthreads();
#pragma unroll 4
        for (int l = 0; l < 32; ++l) {
            const float* rowp = &tile[l * 260];
            float ek = rowp[h * 32 + d];
            const f32x4* vp = (const f32x4*)&rowp[128 + h * 32 + e0];
            f32x4 v0 = vp[0], v1 = vp[1], v2 = vp[2], v3 = vp[3];
            z += ek;
            sacc[0]  += ek * v0[0]; sacc[1]  += ek * v0[1]; sacc[2]  += ek * v0[2]; sacc[3]  += ek * v0[3];
            sacc[4]  += ek * v1[0]; sacc[5]  += ek * v1[1]; sacc[6]  += ek * v1[2]; sacc[7]  += ek * v1[3];
            sacc[8]  += ek * v2[0]; sacc[9]  += ek * v2[1]; sacc[10] += ek * v2[2]; sacc[11] += ek * v2[3];
            sacc[12] += ek * v3[0]; sacc[13] += ek * v3[1]; sacc[14] += ek * v3[2]; sacc[15] += ek * v3[3];
        }
    }
    long sb = (long)blk * 4096 + h * 1024 + d * 32 + e0;
#pragma unroll
    for (int t = 0; t < 16; ++t) S_part[sb + t] = sacc[t];
    if (eg == 0) Z_part[blk * 128 + h * 32 + d] = z;
}

// reduce: S[b][4096] = sum_j S_part[b*128+j][4096]; Z likewise. grid 256.
__global__ __launch_bounds__(256) void reduce_parts(const float* __restrict__ Sp,
                                                    const float* __restrict__ Zp,
                                                    float* __restrict__ S,
                                                    float* __restrict__ Z) {
    int g = blockIdx.x * 256 + threadIdx.x;      // 0..65535
    int b = g >> 12, idx = g & 4095;
    const float* p = Sp + ((long)b * 128) * 4096 + idx;
    float s0 = 0.f, s1 = 0.f;
#pragma unroll 4
    for (int j = 0; j < 64; ++j) { s0 += p[j * 4096]; s1 += p[(j + 64) * 4096]; }
    S[g] = s0 + s1;
    if (g < 2048) {
        int bb = g >> 7, c = g & 127;
        const float* q = Zp + (long)bb * 128 * 128 + c;
        float z0 = 0.f, z1 = 0.f;
#pragma unroll 4
        for (int j = 0; j < 64; ++j) { z0 += q[j * 128]; z1 += q[(j + 64) * 128]; }
        Z[g] = z0 + z1;
    }
}

// combine: ctx = S/Z; M2[b][hd][n] = scale*ctx@W_out. grid 64 (bh).
__global__ __launch_bounds__(256) void combine_kernel(const float* __restrict__ S,
                                                      const float* __restrict__ Z,
                                                      const float* __restrict__ Wout,
                                                      float* __restrict__ m2f) {
    int bh = blockIdx.x;
    int b = bh >> 2, h = bh & 3;
    int n = threadIdx.x;
    __shared__ float ctx[32][33];
    __shared__ float zs[32];
    if (n < 32) zs[n] = Z[b * 128 + h * 32 + n];
    __syncthreads();
#pragma unroll
    for (int t = 0; t < 4; ++t) {
        int idx = t * 256 + n;                  // d*32+e
        ctx[idx >> 5][idx & 31] = S[(long)b * 4096 + h * 1024 + idx] / zs[idx >> 5];
    }
    __syncthreads();
    const float scale = 0.17677669529663687f; // 1/sqrt(32)
    float acc[32];
#pragma unroll
    for (int dd = 0; dd < 32; ++dd) acc[dd] = 0.f;
    for (int e = 0; e < 32; ++e) {
        float w = Wout[(h * 32 + e) * 256 + n];
#pragma unroll
        for (int dd = 0; dd < 32; ++dd) acc[dd] += ctx[dd][e] * w;
    }
#pragma unroll
    for (int dd = 0; dd < 32; ++dd)
        m2f[((long)(b * 128 + h * 32 + dd)) * 256 + n] = acc[dd] * scale;
}

// w2eff: W2[b][k][n] = sum_hd Wq[k][hd]*M2[b][hd][n]; store hi/lo bf16 [b][n][k].
// grid (16 b x 16 kg).
__global__ __launch_bounds__(256) void w2eff_kernel(const float* __restrict__ Wqkv,
                                                    const float* __restrict__ m2f,
                                                    ushort* __restrict__ w2h,
                                                    ushort* __restrict__ w2l) {
    int bid = blockIdx.x;
    int b = bid >> 4, kg = bid & 15;
    int n = threadIdx.x;
    __shared__ float lWq[16 * 128];
#pragma unroll
    for (int u = 0; u < 8; ++u) {
        int idx = u * 256 + n;
        int k = idx >> 7, hd = idx & 127;
        lWq[idx] = Wqkv[(kg * 16 + k) * 384 + hd];   // Wq = cols 0..127
    }
    __syncthreads();
    float acc[16] = {};
    for (int hd = 0; hd < 128; ++hd) {
        float mm = m2f[((long)(b * 128 + hd)) * 256 + n];
#pragma unroll
        for (int k = 0; k < 16; ++k) acc[k] += lWq[k * 128 + hd] * mm;
    }
    long base = ((long)(b * 256 + n)) * 256 + kg * 16;
#pragma unroll
    for (int k = 0; k < 16; ++k) {
        ushort hh = bf16_rn(acc[k]);
        w2h[base + k] = hh;
        w2l[base + k] = bf16_rn(acc[k] - bf16f(hh));
    }
}

// gemm2: out[b] = x[b][8192x256] @ W2[b][256x256] + bias. A fp32 split in-kernel,
// B hi/lo bf16 [n][k]. grid 2048: xcd = wg&7, u = wg>>3, cb = u&1, gid = (u>>1)*8+xcd.
__global__ __launch_bounds__(256) void gemm2_kernel(
    const float* __restrict__ X,
    const ushort* __restrict__ W2h, const ushort* __restrict__ W2l,
    const float* __restrict__ bias, float* __restrict__ out) {
    __shared__ __align__(16) float  As[4096];   // 128r x 32k fp32
    __shared__ __align__(16) ushort Bsh[4096];  // 128r x 32k bf16
    __shared__ __align__(16) ushort Bsl[4096];
    const int tid = threadIdx.x;
    const int wg = blockIdx.x;
    const int xcd = wg & 7;
    const int u = wg >> 3;
    const int cbl = u & 1;
    const int gid = (u >> 1) * 8 + xcd;        // 0..1023
    const long bz = gid >> 6;
    const int row0 = (gid & 63) * 128;
    const int col0 = cbl * 128;
    const float* Xb = X + bz * (8192L * 256);
    const ushort* Bh = W2h + bz * (256L * 256);
    const ushort* Bl = W2l + bz * (256L * 256);
    const int lane = tid & 63, wave = tid >> 6;
    const int wr = (wave & 1) * 64, wc = (wave >> 1) * 64;
    const int m = lane & 15, quad = lane >> 4;
    const int ra = lane >> 3, pa = lane & 7;
    const int rb = lane >> 2, pb = lane & 3;

    f32x4 acc[4][4] = {};

    for (int k0 = 0; k0 < 256; k0 += 32) {
#pragma unroll
        for (int s = 0; s < 4; ++s) {          // A: 16 segs
            int seg = s * 4 + wave;
            int r = seg * 8 + ra;
            int q = pa ^ (r & 7);
            glds16(&Xb[(long)(row0 + r) * 256 + k0 + q * 4], &As[seg * 256]);
        }
#pragma unroll
        for (int s = 0; s < 2; ++s) {          // Bh/Bl: 8 segs each
            int seg = s * 4 + wave;
            int r = seg * 16 + rb;
            int q = pb ^ ((r >> 1) & 3);
            glds16(&Bh[(col0 + r) * 256 + k0 + q * 8], &Bsh[seg * 512]);
            glds16(&Bl[(col0 + r) * 256 + k0 + q * 8], &Bsl[seg * 512]);
        }
        __syncthreads();

        bf16x8 bh[4], bl[4];
#pragma unroll
        for (int j = 0; j < 4; ++j) {
            int r = wc + j * 16 + m;
            int p = quad ^ ((r >> 1) & 3);
            bh[j] = *(const bf16x8*)&Bsh[r * 32 + p * 8];
            bl[j] = *(const bf16x8*)&Bsl[r * 32 + p * 8];
        }
#pragma unroll
        for (int i = 0; i < 4; ++i) {
            int r = wr + i * 16 + m;
            int p0 = (quad * 2) ^ (r & 7);
            int p1 = (quad * 2 + 1) ^ (r & 7);
            f32x4 a0 = *(const f32x4*)&As[r * 32 + p0 * 4];
            f32x4 a1 = *(const f32x4*)&As[r * 32 + p1 * 4];
            u32x4 ahw, alw;
#pragma unroll
            for (int e = 0; e < 2; ++e) {
                float f0 = a0[2 * e], f1 = a0[2 * e + 1];
                unsigned h = cvt_pk2(f0, f1);
                ahw[e] = h;
                alw[e] = cvt_pk2(f0 - __uint_as_float(h << 16),
                                 f1 - __uint_as_float(h & 0xFFFF0000u));
            }
#pragma unroll
            for (int e = 0; e < 2; ++e) {
                float f0 = a1[2 * e], f1 = a1[2 * e + 1];
                unsigned h = cvt_pk2(f0, f1);
                ahw[2 + e] = h;
                alw[2 + e] = cvt_pk2(f0 - __uint_as_float(h << 16),
                                     f1 - __uint_as_float(h & 0xFFFF0000u));
            }
            bf16x8 ah = __builtin_bit_cast(bf16x8, ahw);
            bf16x8 al = __builtin_bit_cast(bf16x8, alw);
#pragma unroll
            for (int j = 0; j < 4; ++j) {
                acc[i][j] = __builtin_amdgcn_mfma_f32_16x16x32_bf16(ah, bh[j], acc[i][j], 0, 0, 0);
                acc[i][j] = __builtin_amdgcn_mfma_f32_16x16x32_bf16(ah, bl[j], acc[i][j], 0, 0, 0);
                acc[i][j] = __builtin_amdgcn_mfma_f32_16x16x32_bf16(al, bh[j], acc[i][j], 0, 0, 0);
            }
        }
        __syncthreads();
    }

    float bv[4];
#pragma unroll
    for (int j = 0; j < 4; ++j) bv[j] = bias[col0 + wc + j * 16 + m];
    float* outb = out + bz * (8192L * 256);
#pragma unroll
    for (int i = 0; i < 4; ++i)
#pragma unroll
        for (int r4 = 0; r4 < 4; ++r4) {
            long row = row0 + wr + i * 16 + quad * 4 + r4;
#pragma unroll
            for (int j = 0; j < 4; ++j)
                outb[row * 256 + col0 + wc + j * 16 + m] = acc[i][j][r4] + bv[j];
        }
}

extern "C" void kernel_launch(void* const* d_in, const int* in_sizes, int n_in,
                              void* d_out, int out_size, void* d_ws, size_t ws_size,
                              hipStream_t stream) {
    const float* x     = (const float*)d_in[0];
    const float* W_qkv = (const float*)d_in[1];
    const float* W_out = (const float*)d_in[2];
    const float* b_out = (const float*)d_in[3];
    float* out = (float*)d_out;

    char* p = (char*)d_ws;
    ushort* wth = (ushort*)p; p += 256 * 256 * 2;            // 128 KB
    ushort* wtl = (ushort*)p; p += 256 * 256 * 2;
    float* Sp   = (float*)p;  p += (long)2048 * 4096 * 4;    // 32 MB
    float* Zp   = (float*)p;  p += 2048 * 128 * 4;           // 1 MB
    float* Sr   = (float*)p;  p += 16 * 4096 * 4;            // 256 KB
    float* Zr   = (float*)p;  p += 2048 * 4;
    float* m2f  = (float*)p;  p += 16 * 128 * 256 * 4;       // 2 MB
    ushort* w2h = (ushort*)p; p += (long)16 * 256 * 256 * 2; // 2 MB
    ushort* w2l = (ushort*)p; p += (long)16 * 256 * 256 * 2;

    prep_kernel<<<256, 256, 0, stream>>>(W_qkv, wth, wtl);
    gemm_kv<<<2048, 256, 0, stream>>>(x, wth, wtl, Sp, Zp);
    reduce_parts<<<256, 256, 0, stream>>>(Sp, Zp, Sr, Zr);
    combine_kernel<<<64, 256, 0, stream>>>(Sr, Zr, W_out, m2f);
    w2eff_kernel<<<256, 256, 0, stream>>>(W_qkv, m2f, w2h, w2l);
    gemm2_kernel<<<2048, 256, 0, stream>>>(x, w2h, w2l, b_out, out);
}

// Round 6
// 355.909 us; speedup vs baseline: 1.0916x; 1.0916x over previous
//
#include <hip/hip_runtime.h>
#include <math.h>

// LinearAttention B=16 L=8192 D=256 H=4 dh=32 — fused-dataflow version
//   prep:    W_qkv cols 128..383 -> WT bf16 (rn) [256 col][256 k]   (kv path is
//            PLAIN bf16: S=sum_l e^k v averages 8192 per-element roundings ->
//            ctx error ~1e-4, negligible vs output tolerance)
//   gemm_kv: per 64-row block: [64x256]@[256x256] bf16 MFMA -> k,v in acc
//            x converted fp32->bf16 ONCE at stage time (reg-stage + ds_write)
//            -> exp(k)|v fp32 tile in LDS (two 32-row half-passes) ->
//            VALU outer-product -> S_part, Z_part (no atomics)
//   reduce:  S = sum_j S_part[j], Z likewise  (coalesced, 256 blocks)
//   combine: ctx = S/Z; M2 = scale*ctx@W_out (fp32)
//   w2eff:   W2[b] = Wq @ M2[b] -> hi/lo bf16 [b][n][k]  (q folded:
//            out = (x@Wq)@M2 = x@(Wq@M2))
//   gemm2:   out[b] = x[b] @ W2[b] + b_out. A = x hi/lo bf16 converted once at
//            stage time (same rn(f), rn(f-hi) values as before — bit-identical);
//            keep 3-term split Ah*Bh+Ah*Bl+Al*Bh for output precision.

typedef __attribute__((ext_vector_type(8))) short bf16x8;
typedef __attribute__((ext_vector_type(4))) float f32x4;
typedef __attribute__((ext_vector_type(4))) unsigned u32x4;

__device__ __forceinline__ unsigned cvt_pk2(float a, float b) {
    unsigned r;
    asm("v_cvt_pk_bf16_f32 %0, %1, %2" : "=v"(r) : "v"(a), "v"(b));
    return r;
}
__device__ __forceinline__ ushort bf16_rn(float f) {
    return (ushort)cvt_pk2(f, f);
}
__device__ __forceinline__ float bf16f(ushort h) { return __uint_as_float(((unsigned)h) << 16); }

__device__ __forceinline__ void glds16(const void* g, void* l) {
    __builtin_amdgcn_global_load_lds((const __attribute__((address_space(1))) unsigned int*)g,
                                     (__attribute__((address_space(3))) unsigned int*)l,
                                     16, 0, 0);
}

// W_qkv [256,384] cols 128..383 -> WT bf16 rn [256 col][256 k]
__global__ __launch_bounds__(256) void prep_kernel(const float* __restrict__ W,
                                                   ushort* __restrict__ wh) {
    int n = blockIdx.x, k = threadIdx.x;          // n: local col (qkv col 128+n)
    wh[n * 256 + k] = bf16_rn(W[k * 384 + 128 + n]);
}

// gemm_kv: grid 2048 (64-row tiles), 256 thr = 4 waves; wave w owns cols w*64..+63.
__global__ __launch_bounds__(256) void gemm_kv(
    const float* __restrict__ X,
    const ushort* __restrict__ Wh,
    float* __restrict__ S_part, float* __restrict__ Z_part) {
    __shared__ __align__(16) char smem[33280];
    ushort* Ash = (ushort*)smem;                // [64r][32k] bf16 = 4 KB, chunk p = q^((r>>1)&3)
    ushort* Bsh = (ushort*)(smem + 4096);       // [256r][32k] bf16 = 16 KB, same swizzle
    float*  tile = (float*)smem;                // epilogue: [32][260] fp32 ek|v = 33280 B

    const int tid = threadIdx.x;
    const int blk = blockIdx.x;
    const long row0 = (long)blk * 64;
    const int lane = tid & 63, wave = tid >> 6;
    const int wc = wave * 64;
    const int m = lane & 15, quad = lane >> 4;
    const int rb = lane >> 2, pb = lane & 3;
    const int rA = tid >> 2, qA = tid & 3;      // A stage: thread -> (row, k-quarter)
    const int pA = qA ^ ((rA >> 1) & 3);

    f32x4 acc[4][4] = {};

    for (int k0 = 0; k0 < 256; k0 += 32) {
        // A: 8 fp32 -> reg (issue first), B: 4 glds16
        const float* xp = &X[(row0 + rA) * 256 + k0 + qA * 8];
        f32x4 x0 = *(const f32x4*)xp;
        f32x4 x1 = *(const f32x4*)(xp + 4);
#pragma unroll
        for (int s = 0; s < 4; ++s) {
            int seg = s * 4 + wave;
            int r = seg * 16 + rb;
            int q = pb ^ ((r >> 1) & 3);
            glds16(&Wh[r * 256 + k0 + q * 8], &Bsh[seg * 512]);
        }
        u32x4 aw;
        aw[0] = cvt_pk2(x0[0], x0[1]); aw[1] = cvt_pk2(x0[2], x0[3]);
        aw[2] = cvt_pk2(x1[0], x1[1]); aw[3] = cvt_pk2(x1[2], x1[3]);
        *(u32x4*)&Ash[rA * 32 + pA * 8] = aw;
        __syncthreads();

        bf16x8 bh[4], av[4];
#pragma unroll
        for (int j = 0; j < 4; ++j) {
            int r = wc + j * 16 + m;
            int p = quad ^ ((r >> 1) & 3);
            bh[j] = *(const bf16x8*)&Bsh[r * 32 + p * 8];
        }
#pragma unroll
        for (int i = 0; i < 4; ++i) {
            int r = i * 16 + m;
            int p = quad ^ ((r >> 1) & 3);
            av[i] = *(const bf16x8*)&Ash[r * 32 + p * 8];
        }
#pragma unroll
        for (int i = 0; i < 4; ++i)
#pragma unroll
            for (int j = 0; j < 4; ++j)
                acc[i][j] = __builtin_amdgcn_mfma_f32_16x16x32_bf16(av[i], bh[j], acc[i][j], 0, 0, 0);
        __syncthreads();
    }

    // epilogue: two 32-row half-passes; tile[32][260] cols 0..127 = e^k, 128..255 = v
    const int h = wave, d = lane >> 1, eg = lane & 1, e0 = eg * 16;
    float sacc[16] = {};
    float z = 0.f;
    for (int half = 0; half < 2; ++half) {
        if (half) __syncthreads();             // all waves done reading pass-0 tile
#pragma unroll
        for (int ii = 0; ii < 2; ++ii) {
            int i = half * 2 + ii;
#pragma unroll
            for (int r4 = 0; r4 < 4; ++r4) {
                int rl = ii * 16 + quad * 4 + r4;     // 0..31
#pragma unroll
                for (int j = 0; j < 4; ++j) {
                    int c = wc + j * 16 + m;
                    float v = acc[i][j][r4];
                    tile[rl * 260 + c] = (c < 128) ? __expf(v) : v;
                }
            }
        }
        __syncthreads();
#pragma unroll 4
        for (int l = 0; l < 32; ++l) {
            const float* rowp = &tile[l * 260];
            float ek = rowp[h * 32 + d];
            const f32x4* vp = (const f32x4*)&rowp[128 + h * 32 + e0];
            f32x4 v0 = vp[0], v1 = vp[1], v2 = vp[2], v3 = vp[3];
            z += ek;
            sacc[0]  += ek * v0[0]; sacc[1]  += ek * v0[1]; sacc[2]  += ek * v0[2]; sacc[3]  += ek * v0[3];
            sacc[4]  += ek * v1[0]; sacc[5]  += ek * v1[1]; sacc[6]  += ek * v1[2]; sacc[7]  += ek * v1[3];
            sacc[8]  += ek * v2[0]; sacc[9]  += ek * v2[1]; sacc[10] += ek * v2[2]; sacc[11] += ek * v2[3];
            sacc[12] += ek * v3[0]; sacc[13] += ek * v3[1]; sacc[14] += ek * v3[2]; sacc[15] += ek * v3[3];
        }
    }
    long sb = (long)blk * 4096 + h * 1024 + d * 32 + e0;
#pragma unroll
    for (int t = 0; t < 16; ++t) S_part[sb + t] = sacc[t];
    if (eg == 0) Z_part[blk * 128 + h * 32 + d] = z;
}

// reduce: S[b][4096] = sum_j S_part[b*128+j][4096]; Z likewise. grid 256.
__global__ __launch_bounds__(256) void reduce_parts(const float* __restrict__ Sp,
                                                    const float* __restrict__ Zp,
                                                    float* __restrict__ S,
                                                    float* __restrict__ Z) {
    int g = blockIdx.x * 256 + threadIdx.x;      // 0..65535
    int b = g >> 12, idx = g & 4095;
    const float* p = Sp + ((long)b * 128) * 4096 + idx;
    float s0 = 0.f, s1 = 0.f;
#pragma unroll 4
    for (int j = 0; j < 64; ++j) { s0 += p[j * 4096]; s1 += p[(j + 64) * 4096]; }
    S[g] = s0 + s1;
    if (g < 2048) {
        int bb = g >> 7, c = g & 127;
        const float* q = Zp + (long)bb * 128 * 128 + c;
        float z0 = 0.f, z1 = 0.f;
#pragma unroll 4
        for (int j = 0; j < 64; ++j) { z0 += q[j * 128]; z1 += q[(j + 64) * 128]; }
        Z[g] = z0 + z1;
    }
}

// combine: ctx = S/Z; M2[b][hd][n] = scale*ctx@W_out. grid 64 (bh).
__global__ __launch_bounds__(256) void combine_kernel(const float* __restrict__ S,
                                                      const float* __restrict__ Z,
                                                      const float* __restrict__ Wout,
                                                      float* __restrict__ m2f) {
    int bh = blockIdx.x;
    int b = bh >> 2, h = bh & 3;
    int n = threadIdx.x;
    __shared__ float ctx[32][33];
    __shared__ float zs[32];
    if (n < 32) zs[n] = Z[b * 128 + h * 32 + n];
    __syncthreads();
#pragma unroll
    for (int t = 0; t < 4; ++t) {
        int idx = t * 256 + n;                  // d*32+e
        ctx[idx >> 5][idx & 31] = S[(long)b * 4096 + h * 1024 + idx] / zs[idx >> 5];
    }
    __syncthreads();
    const float scale = 0.17677669529663687f; // 1/sqrt(32)
    float acc[32];
#pragma unroll
    for (int dd = 0; dd < 32; ++dd) acc[dd] = 0.f;
    for (int e = 0; e < 32; ++e) {
        float w = Wout[(h * 32 + e) * 256 + n];
#pragma unroll
        for (int dd = 0; dd < 32; ++dd) acc[dd] += ctx[dd][e] * w;
    }
#pragma unroll
    for (int dd = 0; dd < 32; ++dd)
        m2f[((long)(b * 128 + h * 32 + dd)) * 256 + n] = acc[dd] * scale;
}

// w2eff: W2[b][k][n] = sum_hd Wq[k][hd]*M2[b][hd][n]; store hi/lo bf16 [b][n][k].
// grid (16 b x 16 kg).
__global__ __launch_bounds__(256) void w2eff_kernel(const float* __restrict__ Wqkv,
                                                    const float* __restrict__ m2f,
                                                    ushort* __restrict__ w2h,
                                                    ushort* __restrict__ w2l) {
    int bid = blockIdx.x;
    int b = bid >> 4, kg = bid & 15;
    int n = threadIdx.x;
    __shared__ float lWq[16 * 128];
#pragma unroll
    for (int u = 0; u < 8; ++u) {
        int idx = u * 256 + n;
        int k = idx >> 7, hd = idx & 127;
        lWq[idx] = Wqkv[(kg * 16 + k) * 384 + hd];   // Wq = cols 0..127
    }
    __syncthreads();
    float acc[16] = {};
    for (int hd = 0; hd < 128; ++hd) {
        float mm = m2f[((long)(b * 128 + hd)) * 256 + n];
#pragma unroll
        for (int k = 0; k < 16; ++k) acc[k] += lWq[k * 128 + hd] * mm;
    }
    long base = ((long)(b * 256 + n)) * 256 + kg * 16;
#pragma unroll
    for (int k = 0; k < 16; ++k) {
        ushort hh = bf16_rn(acc[k]);
        w2h[base + k] = hh;
        w2l[base + k] = bf16_rn(acc[k] - bf16f(hh));
    }
}

// gemm2: out[b] = x[b][8192x256] @ W2[b][256x256] + bias. A = x, converted once at
// stage time into Ash/Asl bf16. B hi/lo bf16 [n][k]. grid 2048 XCD-grouped.
__global__ __launch_bounds__(256) void gemm2_kernel(
    const float* __restrict__ X,
    const ushort* __restrict__ W2h, const ushort* __restrict__ W2l,
    const float* __restrict__ bias, float* __restrict__ out) {
    __shared__ __align__(16) ushort Ash[4096];  // [128r][32k] hi, p = q^((r>>1)&3)
    __shared__ __align__(16) ushort Asl[4096];  // lo
    __shared__ __align__(16) ushort Bsh[4096];
    __shared__ __align__(16) ushort Bsl[4096];
    const int tid = threadIdx.x;
    const int wg = blockIdx.x;
    const int xcd = wg & 7;
    const int u = wg >> 3;
    const int cbl = u & 1;
    const int gid = (u >> 1) * 8 + xcd;        // 0..1023
    const long bz = gid >> 6;
    const int row0 = (gid & 63) * 128;
    const int col0 = cbl * 128;
    const float* Xb = X + bz * (8192L * 256);
    const ushort* Bh = W2h + bz * (256L * 256);
    const ushort* Bl = W2l + bz * (256L * 256);
    const int lane = tid & 63, wave = tid >> 6;
    const int wr = (wave & 1) * 64, wc = (wave >> 1) * 64;
    const int m = lane & 15, quad = lane >> 4;
    const int rb = lane >> 2, pb = lane & 3;

    f32x4 acc[4][4] = {};

    for (int k0 = 0; k0 < 256; k0 += 32) {
        // A: 2 units/thread, 8 fp32 each -> hi/lo bf16 -> LDS
        f32x4 xv[2][2];
#pragma unroll
        for (int t = 0; t < 2; ++t) {
            int uu = t * 256 + tid;
            int r = uu >> 2, q = uu & 3;
            const float* xp = &Xb[(long)(row0 + r) * 256 + k0 + q * 8];
            xv[t][0] = *(const f32x4*)xp;
            xv[t][1] = *(const f32x4*)(xp + 4);
        }
#pragma unroll
        for (int s = 0; s < 2; ++s) {          // Bh/Bl: 8 segs each
            int seg = s * 4 + wave;
            int r = seg * 16 + rb;
            int q = pb ^ ((r >> 1) & 3);
            glds16(&Bh[(col0 + r) * 256 + k0 + q * 8], &Bsh[seg * 512]);
            glds16(&Bl[(col0 + r) * 256 + k0 + q * 8], &Bsl[seg * 512]);
        }
#pragma unroll
        for (int t = 0; t < 2; ++t) {
            int uu = t * 256 + tid;
            int r = uu >> 2, q = uu & 3;
            int p = q ^ ((r >> 1) & 3);
            u32x4 hw, lw;
#pragma unroll
            for (int e = 0; e < 2; ++e) {
                float f0 = xv[t][0][2 * e], f1 = xv[t][0][2 * e + 1];
                unsigned hh = cvt_pk2(f0, f1);
                hw[e] = hh;
                lw[e] = cvt_pk2(f0 - __uint_as_float(hh << 16),
                                f1 - __uint_as_float(hh & 0xFFFF0000u));
            }
#pragma unroll
            for (int e = 0; e < 2; ++e) {
                float f0 = xv[t][1][2 * e], f1 = xv[t][1][2 * e + 1];
                unsigned hh = cvt_pk2(f0, f1);
                hw[2 + e] = hh;
                lw[2 + e] = cvt_pk2(f0 - __uint_as_float(hh << 16),
                                    f1 - __uint_as_float(hh & 0xFFFF0000u));
            }
            *(u32x4*)&Ash[r * 32 + p * 8] = hw;
            *(u32x4*)&Asl[r * 32 + p * 8] = lw;
        }
        __syncthreads();

        bf16x8 af[2][4], bg[2][4];
#pragma unroll
        for (int i = 0; i < 4; ++i) {
            int rA = wr + i * 16 + m;
            int pA = quad ^ ((rA >> 1) & 3);
            af[0][i] = *(const bf16x8*)&Ash[rA * 32 + pA * 8];
            af[1][i] = *(const bf16x8*)&Asl[rA * 32 + pA * 8];
            int rB = wc + i * 16 + m;
            int pB = quad ^ ((rB >> 1) & 3);
            bg[0][i] = *(const bf16x8*)&Bsh[rB * 32 + pB * 8];
            bg[1][i] = *(const bf16x8*)&Bsl[rB * 32 + pB * 8];
        }
#pragma unroll
        for (int i = 0; i < 4; ++i)
#pragma unroll
            for (int j = 0; j < 4; ++j) {
                acc[i][j] = __builtin_amdgcn_mfma_f32_16x16x32_bf16(af[0][i], bg[0][j], acc[i][j], 0, 0, 0);
                acc[i][j] = __builtin_amdgcn_mfma_f32_16x16x32_bf16(af[0][i], bg[1][j], acc[i][j], 0, 0, 0);
                acc[i][j] = __builtin_amdgcn_mfma_f32_16x16x32_bf16(af[1][i], bg[0][j], acc[i][j], 0, 0, 0);
            }
        __syncthreads();
    }

    float bv[4];
#pragma unroll
    for (int j = 0; j < 4; ++j) bv[j] = bias[col0 + wc + j * 16 + m];
    float* outb = out + bz * (8192L * 256);
#pragma unroll
    for (int i = 0; i < 4; ++i)
#pragma unroll
        for (int r4 = 0; r4 < 4; ++r4) {
            long row = row0 + wr + i * 16 + quad * 4 + r4;
#pragma unroll
            for (int j = 0; j < 4; ++j)
                outb[row * 256 + col0 + wc + j * 16 + m] = acc[i][j][r4] + bv[j];
        }
}

extern "C" void kernel_launch(void* const* d_in, const int* in_sizes, int n_in,
                              void* d_out, int out_size, void* d_ws, size_t ws_size,
                              hipStream_t stream) {
    const float* x     = (const float*)d_in[0];
    const float* W_qkv = (const float*)d_in[1];
    const float* W_out = (const float*)d_in[2];
    const float* b_out = (const float*)d_in[3];
    float* out = (float*)d_out;

    char* p = (char*)d_ws;
    ushort* wth = (ushort*)p; p += 256 * 256 * 2;            // 128 KB
    float* Sp   = (float*)p;  p += (long)2048 * 4096 * 4;    // 32 MB
    float* Zp   = (float*)p;  p += 2048 * 128 * 4;           // 1 MB
    float* Sr   = (float*)p;  p += 16 * 4096 * 4;            // 256 KB
    float* Zr   = (float*)p;  p += 2048 * 4;
    float* m2f  = (float*)p;  p += 16 * 128 * 256 * 4;       // 2 MB
    ushort* w2h = (ushort*)p; p += (long)16 * 256 * 256 * 2; // 2 MB
    ushort* w2l = (ushort*)p; p += (long)16 * 256 * 256 * 2;

    prep_kernel<<<256, 256, 0, stream>>>(W_qkv, wth);
    gemm_kv<<<2048, 256, 0, stream>>>(x, wth, Sp, Zp);
    reduce_parts<<<256, 256, 0, stream>>>(Sp, Zp, Sr, Zr);
    combine_kernel<<<64, 256, 0, stream>>>(Sr, Zr, W_out, m2f);
    w2eff_kernel<<<256, 256, 0, stream>>>(W_qkv, m2f, w2h, w2l);
    gemm2_kernel<<<2048, 256, 0, stream>>>(x, w2h, w2l, b_out, out);
}